// Round 8
// baseline (607.197 us; speedup 1.0000x reference)
//
#include <hip/hip_runtime.h>

typedef unsigned short u16;
typedef __bf16 bf16x8 __attribute__((ext_vector_type(8)));
typedef float f32x4 __attribute__((ext_vector_type(4)));
typedef u16 u16x4 __attribute__((ext_vector_type(4)));
typedef u16 u16x8 __attribute__((ext_vector_type(8)));

#define SCALE 0.17677669529663687f  // 32^-0.5

__device__ __forceinline__ u16 f2bf(float f) {
  union { float f; unsigned u; } v; v.f = f;
  unsigned r = v.u + 0x7fffu + ((v.u >> 16) & 1u);
  return (u16)(r >> 16);
}

__device__ __forceinline__ void gload_lds16(const void* g, void* l) {
  __builtin_amdgcn_global_load_lds(
      (const __attribute__((address_space(1))) unsigned int*)g,
      (__attribute__((address_space(3))) unsigned int*)l, 16, 0, 0);
}

// ---------------- conversion kernels ----------------
__global__ __launch_bounds__(256) void conv_x_k(const float* __restrict__ in,
                                                u16* __restrict__ out) {
  size_t id = (size_t)blockIdx.x * 256 + threadIdx.x;
  const f32x4* p = (const f32x4*)(in + id * 8);
  f32x4 a = p[0], c = p[1];
  u16x8 r;
  r[0] = f2bf(a[0]); r[1] = f2bf(a[1]); r[2] = f2bf(a[2]); r[3] = f2bf(a[3]);
  r[4] = f2bf(c[0]); r[5] = f2bf(c[1]); r[6] = f2bf(c[2]); r[7] = f2bf(c[3]);
  *(u16x8*)(out + id * 8) = r;
}

// W [512][N] fp32 -> WT [N][512] bf16
__global__ __launch_bounds__(256) void conv_wT_k(const float* __restrict__ W,
                                                 u16* __restrict__ WT, int N) {
  int id = blockIdx.x * 256 + threadIdx.x;
  int n = id >> 9, k = id & 511;
  WT[id] = f2bf(W[(size_t)k * N + n]);
}

// ---------------- GEMM: C[m][n] = sum_k A[m][k]*Bt[n][k] ----------------
// MODE 0: A=xb, N=1536 (cols 0-511 Wq -> qbuf scaled; 512-1023 -> kbuf; 1024-1535 -> vt)
// MODE 1: A=attn_out, N=512 (WpT) -> fp32 out + bias
// XCD-locality swizzle (kept; FETCH 400->59MB measured) + T3-min double-buffered
// pipeline: STAGE(kt+1) issued BEFORE compute(kt), ONE barrier per K-step, so
// staging-load latency hides under ds_read+MFMA instead of sitting on the
// critical path (round-7 PMC: MfmaUtil 19%, occupancy 21% -> latency-bound).
template <int MODE>
__global__ __launch_bounds__(256) void gemm_k(
    const u16* __restrict__ A, const u16* __restrict__ B0,
    const u16* __restrict__ B1, const float* __restrict__ bias0,
    const float* __restrict__ bias1, u16* __restrict__ qbuf,
    u16* __restrict__ kbuf, u16* __restrict__ vtbuf, float* __restrict__ outp) {
  __shared__ __align__(16) u16 lA[2][128 * 32];
  __shared__ __align__(16) u16 lB[2][128 * 32];
  const int tid = threadIdx.x;
  const int w = tid >> 6, l = tid & 63;

  constexpr int NT = (MODE == 0) ? 12 : 4;  // n-tiles of 128
  const int bid = blockIdx.x;
  const int xcd = bid & 7;
  const int local = bid >> 3;           // 0 .. (nwg/8)-1
  const int n_idx = local % NT;         // fastest: n within the XCD chunk
  const int m_idx = xcd * 64 + local / NT;  // 512 m-panels / 8 XCDs = 64 each
  const int m0 = m_idx * 128;
  const int n0 = n_idx * 128;

  const u16* Bt;
  if (MODE == 0)
    Bt = (n_idx < 4) ? (B0 + (size_t)n0 * 512) : (B1 + (size_t)(n0 - 512) * 512);
  else
    Bt = B0 + (size_t)n0 * 512;

  f32x4 acc[4][4];
#pragma unroll
  for (int i = 0; i < 4; ++i)
#pragma unroll
    for (int j = 0; j < 4; ++j) acc[i][j] = f32x4{0.f, 0.f, 0.f, 0.f};

  const int lr = l >> 2, ls = l & 3;
  const int wm = w >> 1, wn = w & 1;
  const int fr = l & 15, kc = l >> 4;

  // staging: each wave fills rows [w*32, w*32+32) of the 128x32 tile
  auto STAGE = [&](int kt, int buf) {
    const int k0 = kt * 32;
#pragma unroll
    for (int i = 0; i < 2; ++i) {
      int row = w * 32 + i * 16 + lr;
      int ca = ls ^ (row & 3);  // inverse-swizzled global source, linear LDS dest
      gload_lds16(A + (size_t)(m0 + row) * 512 + k0 + ca * 8,
                  &lA[buf][(w * 32 + i * 16) * 32]);
      gload_lds16(Bt + (size_t)row * 512 + k0 + ca * 8,
                  &lB[buf][(w * 32 + i * 16) * 32]);
    }
  };

  STAGE(0, 0);
  __syncthreads();

  int cur = 0;
#pragma unroll 2
  for (int kt = 0; kt < 16; ++kt) {
    if (kt < 15) STAGE(kt + 1, cur ^ 1);  // prefetch next tile into other buffer
    bf16x8 af[4], bfr[4];
#pragma unroll
    for (int t = 0; t < 4; ++t) {
      int ra = wm * 64 + t * 16 + fr;
      af[t] = *(const bf16x8*)&lA[cur][ra * 32 + ((kc ^ (ra & 3)) * 8)];
      int rb = wn * 64 + t * 16 + fr;
      bfr[t] = *(const bf16x8*)&lB[cur][rb * 32 + ((kc ^ (rb & 3)) * 8)];
    }
#pragma unroll
    for (int i = 0; i < 4; ++i)
#pragma unroll
      for (int j = 0; j < 4; ++j)
        acc[i][j] = __builtin_amdgcn_mfma_f32_16x16x32_bf16(af[i], bfr[j],
                                                            acc[i][j], 0, 0, 0);
    __syncthreads();  // next buffer landed; cur reads done before overwrite
    cur ^= 1;
  }

  const int m_base = m0 + wm * 64;
  const int n_base = n0 + wn * 64;
  const int rowg = kc * 4;

  if (MODE == 1) {
#pragma unroll
    for (int i = 0; i < 4; ++i)
#pragma unroll
      for (int j = 0; j < 4; ++j) {
        int n = n_base + j * 16 + fr;
        float bb = bias0[n];
#pragma unroll
        for (int r = 0; r < 4; ++r) {
          int m = m_base + i * 16 + rowg + r;
          outp[(size_t)m * 512 + n] = acc[i][j][r] + bb;
        }
      }
  } else {
    const int b = m_base >> 6;  // window index, constant per wave
#pragma unroll
    for (int i = 0; i < 4; ++i) {
      int tok0 = i * 16 + rowg;
#pragma unroll
      for (int j = 0; j < 4; ++j) {
        int n = n_base + j * 16 + fr;
        if (n < 512) {  // Q, fold softmax scale
          int h = n >> 5, d = n & 31;
          float bb = bias0[n];
          u16* dst = qbuf + (size_t)(b * 16 + h) * 2048 + d;
#pragma unroll
          for (int r = 0; r < 4; ++r)
            dst[(tok0 + r) * 32] = f2bf((acc[i][j][r] + bb) * SCALE);
        } else if (n < 1024) {  // K
          int nk = n - 512, h = nk >> 5, d = nk & 31;
          float bb = bias1[nk];
          u16* dst = kbuf + (size_t)(b * 16 + h) * 2048 + d;
#pragma unroll
          for (int r = 0; r < 4; ++r) dst[(tok0 + r) * 32] = f2bf(acc[i][j][r] + bb);
        } else {  // V, stored transposed [b,h,d,tok]
          int nv = n - 512, h = (nv - 512) >> 5, d = n & 31;
          float bb = bias1[nv];
          u16x4 pk;
#pragma unroll
          for (int r = 0; r < 4; ++r) pk[r] = f2bf(acc[i][j][r] + bb);
          *(u16x4*)(vtbuf + (size_t)(b * 16 + h) * 2048 + (size_t)d * 64 + tok0) = pk;
        }
      }
    }
  }
}

// ---------------- attention: 1 block per (b,h), 4 waves x 16-row strips ------
__global__ __launch_bounds__(256) void attn_k(
    const u16* __restrict__ qbuf, const u16* __restrict__ kbuf,
    const u16* __restrict__ vtbuf, const float* __restrict__ mask,
    u16* __restrict__ aout) {
  __shared__ __align__(16) u16 plds[4 * 1024];  // 4 waves x 16x64 bf16
  const int tid = threadIdx.x;
  const int wv = tid >> 6, l = tid & 63;
  const int bh = blockIdx.x;
  const int b = bh >> 4, h = bh & 15;
  const int fr = l & 15, kc = l >> 4;
  const size_t base = (size_t)bh * 2048;
  const u16* qp = qbuf + base;
  const u16* kp = kbuf + base;
  const u16* vp = vtbuf + base;

  // QK^T for this wave's 16-row strip (scale pre-folded into q)
  bf16x8 qf = *(const bf16x8*)(qp + (wv * 16 + fr) * 32 + kc * 8);
  f32x4 s[4];
#pragma unroll
  for (int j = 0; j < 4; ++j) {
    bf16x8 kf = *(const bf16x8*)(kp + (j * 16 + fr) * 32 + kc * 8);
    s[j] = __builtin_amdgcn_mfma_f32_16x16x32_bf16(qf, kf, f32x4{0.f, 0.f, 0.f, 0.f},
                                                   0, 0, 0);
  }

  // + mask, wave-parallel softmax (rows live across 16-lane groups)
  const float* mp = mask + (size_t)(b & 255) * 4096 + (size_t)(wv * 16 + kc * 4) * 64 + fr;
  float p[4][4], rinv[4];
#pragma unroll
  for (int r = 0; r < 4; ++r) {
    float mx = -1e30f;
#pragma unroll
    for (int j = 0; j < 4; ++j) {
      float t = s[j][r] + mp[r * 64 + j * 16];
      p[j][r] = t;
      mx = fmaxf(mx, t);
    }
#pragma unroll
    for (int d = 1; d < 16; d <<= 1) mx = fmaxf(mx, __shfl_xor(mx, d));
    float sum = 0.f;
#pragma unroll
    for (int j = 0; j < 4; ++j) {
      float e = __expf(p[j][r] - mx);
      p[j][r] = e;
      sum += e;
    }
#pragma unroll
    for (int d = 1; d < 16; d <<= 1) sum += __shfl_xor(sum, d);
    rinv[r] = 1.f / sum;
  }

  // P -> LDS (XOR-swizzled rows, 16B-chunk granularity)
  char* pbase = (char*)plds + wv * 2048;
#pragma unroll
  for (int r = 0; r < 4; ++r) {
    int rl = kc * 4 + r;
    unsigned swz = (unsigned)(rl & 7) << 4;
#pragma unroll
    for (int j = 0; j < 4; ++j) {
      unsigned byte = (unsigned)rl * 128 + ((((unsigned)(j * 16 + fr)) * 2) ^ swz);
      *(u16*)(pbase + byte) = f2bf(p[j][r]);
    }
  }
  __syncthreads();

  // PV: O[16x32] = P[16x64] @ V[64x32]  (V stored transposed -> contiguous B frags)
  f32x4 o[2] = {f32x4{0.f, 0.f, 0.f, 0.f}, f32x4{0.f, 0.f, 0.f, 0.f}};
#pragma unroll
  for (int kk = 0; kk < 2; ++kk) {
    unsigned byte =
        (unsigned)fr * 128 + (((unsigned)(kk * 64 + kc * 16)) ^ ((unsigned)(fr & 7) << 4));
    bf16x8 pf = *(const bf16x8*)(pbase + byte);
#pragma unroll
    for (int j = 0; j < 2; ++j) {
      bf16x8 vf = *(const bf16x8*)(vp + (j * 16 + fr) * 64 + kk * 32 + kc * 8);
      o[j] = __builtin_amdgcn_mfma_f32_16x16x32_bf16(pf, vf, o[j], 0, 0, 0);
    }
  }

  // normalize by row-sum, store bf16 [m=b*64+tok][c=h*32+d]
#pragma unroll
  for (int j = 0; j < 2; ++j)
#pragma unroll
    for (int r = 0; r < 4; ++r) {
      int tok = wv * 16 + kc * 4 + r;
      int d = j * 16 + fr;
      aout[((size_t)(b * 64 + tok)) * 512 + h * 32 + d] = f2bf(o[j][r] * rinv[r]);
    }
}

// ---------------- launch ----------------
extern "C" void kernel_launch(void* const* d_in, const int* in_sizes, int n_in,
                              void* d_out, int out_size, void* d_ws, size_t ws_size,
                              hipStream_t stream) {
  const float* x    = (const float*)d_in[0];
  const float* mask = (const float*)d_in[1];
  const float* Wq   = (const float*)d_in[2];
  const float* bq   = (const float*)d_in[3];
  const float* Wkv  = (const float*)d_in[4];
  const float* bkv  = (const float*)d_in[5];
  const float* Wp   = (const float*)d_in[6];
  const float* bp   = (const float*)d_in[7];
  float* out = (float*)d_out;
  char* ws = (char*)d_ws;
  const size_t SEG = 67108864;  // 65536*512*2 bytes
  u16* xb   = (u16*)ws;             // x bf16; reused as attn_out after QKV GEMM
  u16* qb   = (u16*)(ws + SEG);     // [b,h,n,d] * SCALE
  u16* kb   = (u16*)(ws + 2 * SEG); // [b,h,n,d]
  u16* vtb  = (u16*)(ws + 3 * SEG); // [b,h,d,n]
  u16* WqT  = (u16*)(ws + 4 * SEG);
  u16* WkvT = WqT + 512 * 512;
  u16* WpT  = WkvT + 512 * 1024;

  conv_x_k<<<16384, 256, 0, stream>>>(x, xb);
  conv_wT_k<<<1024, 256, 0, stream>>>(Wq, WqT, 512);
  conv_wT_k<<<2048, 256, 0, stream>>>(Wkv, WkvT, 1024);
  conv_wT_k<<<1024, 256, 0, stream>>>(Wp, WpT, 512);
  gemm_k<0><<<6144, 256, 0, stream>>>(xb, WqT, WkvT, bq, bkv, qb, kb,
                                      vtb, nullptr);
  attn_k<<<16384, 256, 0, stream>>>(qb, kb, vtb, mask, xb);
  gemm_k<1><<<2048, 256, 0, stream>>>(xb, WpT, nullptr, bp, nullptr,
                                      nullptr, nullptr, nullptr, out);
}

// Round 11
// 551.923 us; speedup vs baseline: 1.1001x; 1.1001x over previous
//
#include <hip/hip_runtime.h>

typedef unsigned short u16;
typedef __bf16 bf16x8 __attribute__((ext_vector_type(8)));
typedef float f32x4 __attribute__((ext_vector_type(4)));
typedef u16 u16x4 __attribute__((ext_vector_type(4)));
typedef u16 u16x8 __attribute__((ext_vector_type(8)));

#define SCALE 0.17677669529663687f  // 32^-0.5

__device__ __forceinline__ u16 f2bf(float f) {
  union { float f; unsigned u; } v; v.f = f;
  unsigned r = v.u + 0x7fffu + ((v.u >> 16) & 1u);
  return (u16)(r >> 16);
}

__device__ __forceinline__ void gload_lds16(const void* g, void* l) {
  __builtin_amdgcn_global_load_lds(
      (const __attribute__((address_space(1))) unsigned int*)g,
      (__attribute__((address_space(3))) unsigned int*)l, 16, 0, 0);
}

// ---------------- conversion kernels ----------------
__global__ __launch_bounds__(256) void conv_x_k(const float* __restrict__ in,
                                                u16* __restrict__ out) {
  size_t id = (size_t)blockIdx.x * 256 + threadIdx.x;
  const f32x4* p = (const f32x4*)(in + id * 8);
  f32x4 a = p[0], c = p[1];
  u16x8 r;
  r[0] = f2bf(a[0]); r[1] = f2bf(a[1]); r[2] = f2bf(a[2]); r[3] = f2bf(a[3]);
  r[4] = f2bf(c[0]); r[5] = f2bf(c[1]); r[6] = f2bf(c[2]); r[7] = f2bf(c[3]);
  *(u16x8*)(out + id * 8) = r;
}

// W [512][N] fp32 -> WT [N][512] bf16
__global__ __launch_bounds__(256) void conv_wT_k(const float* __restrict__ W,
                                                 u16* __restrict__ WT, int N) {
  int id = blockIdx.x * 256 + threadIdx.x;
  int n = id >> 9, k = id & 511;
  WT[id] = f2bf(W[(size_t)k * N + n]);
}

// ---------------- GEMM: C[m][n] = sum_k A[m][k]*Bt[n][k] ----------------
// MODE 0: A=xb, N=1536 (cols 0-511 Wq -> qbuf scaled; 512-1023 -> kbuf; 1024-1535 -> vt)
// MODE 1: A=attn_out, N=512 (WpT) -> fp32 out + bias
// R9: XCD swizzle (kept) + dbuf 1-barrier (kept) + HOISTED addressing (R8 PMC:
// VALUBusy 33% from recomputed addresses -> pointer bumps + ds offset imms) +
// __launch_bounds__(256,3): R8 was 108 VGPR + 64 AGPR = 172, 2 regs over the
// 3-waves/SIMD boundary (170) -> force 3 blocks/CU on a latency-bound kernel.
template <int MODE>
__global__ __launch_bounds__(256, 3) void gemm_k(
    const u16* __restrict__ A, const u16* __restrict__ B0,
    const u16* __restrict__ B1, const float* __restrict__ bias0,
    const float* __restrict__ bias1, u16* __restrict__ qbuf,
    u16* __restrict__ kbuf, u16* __restrict__ vtbuf, float* __restrict__ outp) {
  __shared__ __align__(16) u16 lA[2][128 * 32];
  __shared__ __align__(16) u16 lB[2][128 * 32];
  const int tid = threadIdx.x;
  const int w = tid >> 6, l = tid & 63;

  constexpr int NT = (MODE == 0) ? 12 : 4;  // n-tiles of 128
  const int bid = blockIdx.x;
  const int xcd = bid & 7;
  const int local = bid >> 3;
  const int n_idx = local % NT;             // fastest: n within the XCD chunk
  const int m_idx = xcd * 64 + local / NT;  // 512 m-panels / 8 XCDs = 64 each
  const int m0 = m_idx * 128;
  const int n0 = n_idx * 128;

  const u16* Bt;
  if (MODE == 0)
    Bt = (n_idx < 4) ? (B0 + (size_t)n0 * 512) : (B1 + (size_t)(n0 - 512) * 512);
  else
    Bt = B0 + (size_t)n0 * 512;

  f32x4 acc[4][4];
#pragma unroll
  for (int i = 0; i < 4; ++i)
#pragma unroll
    for (int j = 0; j < 4; ++j) acc[i][j] = f32x4{0.f, 0.f, 0.f, 0.f};

  const int lr = l >> 2, ls = l & 3;
  const int wm = w >> 1, wn = w & 1;
  const int fr = l & 15, kc = l >> 4;

  // ---- hoisted staging addresses (advance by 32 elems / 64 B per K-step) ----
  const int ca = ls ^ (lr & 3);  // inverse-swizzled source chunk (row&3 == lr&3)
  const int srow0 = w * 32 + lr, srow1 = srow0 + 16;
  const u16* pA0 = A + (size_t)(m0 + srow0) * 512 + ca * 8;
  const u16* pA1 = A + (size_t)(m0 + srow1) * 512 + ca * 8;
  const u16* pB0 = Bt + (size_t)srow0 * 512 + ca * 8;
  const u16* pB1 = Bt + (size_t)srow1 * 512 + ca * 8;
  const int dRow0 = (w * 32) * 32, dRow1 = (w * 32 + 16) * 32;  // wave-uniform

  // ---- hoisted LDS read bases (kt-invariant; t adds 512 elems -> ds offset imm)
  const int swz = (kc ^ (fr & 3)) * 8;
  const int eA = (wm * 64 + fr) * 32 + swz;
  const int eB = (wn * 64 + fr) * 32 + swz;

  // prologue: stage tile 0 into buf 0
  gload_lds16(pA0, &lA[0][dRow0]);
  gload_lds16(pA1, &lA[0][dRow1]);
  gload_lds16(pB0, &lB[0][dRow0]);
  gload_lds16(pB1, &lB[0][dRow1]);
  __syncthreads();

  int cur = 0;
#pragma unroll 2
  for (int kt = 0; kt < 16; ++kt) {
    if (kt < 15) {  // prefetch next tile into other buffer (4 pointer bumps)
      pA0 += 32; pA1 += 32; pB0 += 32; pB1 += 32;
      gload_lds16(pA0, &lA[cur ^ 1][dRow0]);
      gload_lds16(pA1, &lA[cur ^ 1][dRow1]);
      gload_lds16(pB0, &lB[cur ^ 1][dRow0]);
      gload_lds16(pB1, &lB[cur ^ 1][dRow1]);
    }
    bf16x8 af[4], bfr[4];
#pragma unroll
    for (int t = 0; t < 4; ++t) {
      af[t] = *(const bf16x8*)&lA[cur][eA + t * 512];
      bfr[t] = *(const bf16x8*)&lB[cur][eB + t * 512];
    }
#pragma unroll
    for (int i = 0; i < 4; ++i)
#pragma unroll
      for (int j = 0; j < 4; ++j)
        acc[i][j] = __builtin_amdgcn_mfma_f32_16x16x32_bf16(af[i], bfr[j],
                                                            acc[i][j], 0, 0, 0);
    __syncthreads();  // next buffer landed; cur reads done before overwrite
    cur ^= 1;
  }

  const int m_base = m0 + wm * 64;
  const int n_base = n0 + wn * 64;
  const int rowg = kc * 4;

  if (MODE == 1) {
#pragma unroll
    for (int i = 0; i < 4; ++i)
#pragma unroll
      for (int j = 0; j < 4; ++j) {
        int n = n_base + j * 16 + fr;
        float bb = bias0[n];
#pragma unroll
        for (int r = 0; r < 4; ++r) {
          int m = m_base + i * 16 + rowg + r;
          outp[(size_t)m * 512 + n] = acc[i][j][r] + bb;
        }
      }
  } else {
    const int b = m_base >> 6;  // window index, constant per wave
#pragma unroll
    for (int i = 0; i < 4; ++i) {
      int tok0 = i * 16 + rowg;
#pragma unroll
      for (int j = 0; j < 4; ++j) {
        int n = n_base + j * 16 + fr;
        if (n < 512) {  // Q, fold softmax scale
          int h = n >> 5, d = n & 31;
          float bb = bias0[n];
          u16* dst = qbuf + (size_t)(b * 16 + h) * 2048 + d;
#pragma unroll
          for (int r = 0; r < 4; ++r)
            dst[(tok0 + r) * 32] = f2bf((acc[i][j][r] + bb) * SCALE);
        } else if (n < 1024) {  // K
          int nk = n - 512, h = nk >> 5, d = nk & 31;
          float bb = bias1[nk];
          u16* dst = kbuf + (size_t)(b * 16 + h) * 2048 + d;
#pragma unroll
          for (int r = 0; r < 4; ++r) dst[(tok0 + r) * 32] = f2bf(acc[i][j][r] + bb);
        } else {  // V, stored transposed [b,h,d,tok]
          int nv = n - 512, h = (nv - 512) >> 5, d = n & 31;
          float bb = bias1[nv];
          u16x4 pk;
#pragma unroll
          for (int r = 0; r < 4; ++r) pk[r] = f2bf(acc[i][j][r] + bb);
          *(u16x4*)(vtbuf + (size_t)(b * 16 + h) * 2048 + (size_t)d * 64 + tok0) = pk;
        }
      }
    }
  }
}

// ---------------- attention: 1 block per (b,h), 4 waves x 16-row strips ------
__global__ __launch_bounds__(256) void attn_k(
    const u16* __restrict__ qbuf, const u16* __restrict__ kbuf,
    const u16* __restrict__ vtbuf, const float* __restrict__ mask,
    u16* __restrict__ aout) {
  __shared__ __align__(16) u16 plds[4 * 1024];  // 4 waves x 16x64 bf16
  const int tid = threadIdx.x;
  const int wv = tid >> 6, l = tid & 63;
  const int bh = blockIdx.x;
  const int b = bh >> 4, h = bh & 15;
  const int fr = l & 15, kc = l >> 4;
  const size_t base = (size_t)bh * 2048;
  const u16* qp = qbuf + base;
  const u16* kp = kbuf + base;
  const u16* vp = vtbuf + base;

  // QK^T for this wave's 16-row strip (scale pre-folded into q)
  bf16x8 qf = *(const bf16x8*)(qp + (wv * 16 + fr) * 32 + kc * 8);
  f32x4 s[4];
#pragma unroll
  for (int j = 0; j < 4; ++j) {
    bf16x8 kf = *(const bf16x8*)(kp + (j * 16 + fr) * 32 + kc * 8);
    s[j] = __builtin_amdgcn_mfma_f32_16x16x32_bf16(qf, kf, f32x4{0.f, 0.f, 0.f, 0.f},
                                                   0, 0, 0);
  }

  // + mask, wave-parallel softmax (rows live across 16-lane groups)
  const float* mp = mask + (size_t)(b & 255) * 4096 + (size_t)(wv * 16 + kc * 4) * 64 + fr;
  float p[4][4], rinv[4];
#pragma unroll
  for (int r = 0; r < 4; ++r) {
    float mx = -1e30f;
#pragma unroll
    for (int j = 0; j < 4; ++j) {
      float t = s[j][r] + mp[r * 64 + j * 16];
      p[j][r] = t;
      mx = fmaxf(mx, t);
    }
#pragma unroll
    for (int d = 1; d < 16; d <<= 1) mx = fmaxf(mx, __shfl_xor(mx, d));
    float sum = 0.f;
#pragma unroll
    for (int j = 0; j < 4; ++j) {
      float e = __expf(p[j][r] - mx);
      p[j][r] = e;
      sum += e;
    }
#pragma unroll
    for (int d = 1; d < 16; d <<= 1) sum += __shfl_xor(sum, d);
    rinv[r] = 1.f / sum;
  }

  // P -> LDS (XOR-swizzled rows, 16B-chunk granularity)
  char* pbase = (char*)plds + wv * 2048;
#pragma unroll
  for (int r = 0; r < 4; ++r) {
    int rl = kc * 4 + r;
    unsigned swz = (unsigned)(rl & 7) << 4;
#pragma unroll
    for (int j = 0; j < 4; ++j) {
      unsigned byte = (unsigned)rl * 128 + ((((unsigned)(j * 16 + fr)) * 2) ^ swz);
      *(u16*)(pbase + byte) = f2bf(p[j][r]);
    }
  }
  __syncthreads();

  // PV: O[16x32] = P[16x64] @ V[64x32]  (V stored transposed -> contiguous B frags)
  f32x4 o[2] = {f32x4{0.f, 0.f, 0.f, 0.f}, f32x4{0.f, 0.f, 0.f, 0.f}};
#pragma unroll
  for (int kk = 0; kk < 2; ++kk) {
    unsigned byte =
        (unsigned)fr * 128 + (((unsigned)(kk * 64 + kc * 16)) ^ ((unsigned)(fr & 7) << 4));
    bf16x8 pf = *(const bf16x8*)(pbase + byte);
#pragma unroll
    for (int j = 0; j < 2; ++j) {
      bf16x8 vf = *(const bf16x8*)(vp + (j * 16 + fr) * 64 + kk * 32 + kc * 8);
      o[j] = __builtin_amdgcn_mfma_f32_16x16x32_bf16(pf, vf, o[j], 0, 0, 0);
    }
  }

  // normalize by row-sum, store bf16 [m=b*64+tok][c=h*32+d]
#pragma unroll
  for (int j = 0; j < 2; ++j)
#pragma unroll
    for (int r = 0; r < 4; ++r) {
      int tok = wv * 16 + kc * 4 + r;
      int d = j * 16 + fr;
      aout[((size_t)(b * 64 + tok)) * 512 + h * 32 + d] = f2bf(o[j][r] * rinv[r]);
    }
}

// ---------------- launch ----------------
extern "C" void kernel_launch(void* const* d_in, const int* in_sizes, int n_in,
                              void* d_out, int out_size, void* d_ws, size_t ws_size,
                              hipStream_t stream) {
  const float* x    = (const float*)d_in[0];
  const float* mask = (const float*)d_in[1];
  const float* Wq   = (const float*)d_in[2];
  const float* bq   = (const float*)d_in[3];
  const float* Wkv  = (const float*)d_in[4];
  const float* bkv  = (const float*)d_in[5];
  const float* Wp   = (const float*)d_in[6];
  const float* bp   = (const float*)d_in[7];
  float* out = (float*)d_out;
  char* ws = (char*)d_ws;
  const size_t SEG = 67108864;  // 65536*512*2 bytes
  u16* xb   = (u16*)ws;             // x bf16; reused as attn_out after QKV GEMM
  u16* qb   = (u16*)(ws + SEG);     // [b,h,n,d] * SCALE
  u16* kb   = (u16*)(ws + 2 * SEG); // [b,h,n,d]
  u16* vtb  = (u16*)(ws + 3 * SEG); // [b,h,d,n]
  u16* WqT  = (u16*)(ws + 4 * SEG);
  u16* WkvT = WqT + 512 * 512;
  u16* WpT  = WkvT + 512 * 1024;

  conv_x_k<<<16384, 256, 0, stream>>>(x, xb);
  conv_wT_k<<<1024, 256, 0, stream>>>(Wq, WqT, 512);
  conv_wT_k<<<2048, 256, 0, stream>>>(Wkv, WkvT, 1024);
  conv_wT_k<<<1024, 256, 0, stream>>>(Wp, WpT, 512);
  gemm_k<0><<<6144, 256, 0, stream>>>(xb, WqT, WkvT, bq, bkv, qb, kb,
                                      vtb, nullptr);
  attn_k<<<16384, 256, 0, stream>>>(qb, kb, vtb, mask, xb);
  gemm_k<1><<<2048, 256, 0, stream>>>(xb, WpT, nullptr, bp, nullptr,
                                      nullptr, nullptr, nullptr, out);
}